// Round 1
// baseline (490.185 us; speedup 1.0000x reference)
//
#include <hip/hip_runtime.h>
#include <stdint.h>

#define BB 8
#define NN 2048
#define MM 2048
#define KK 256
#define NMTOT (NN*MM)
#define NBIN 8192
#define CANDCAP 4096

typedef unsigned int u32;
typedef unsigned long long u64;

__device__ inline double dshflxor(double x, int m) {
  long long v = __double_as_longlong(x);
  int lo = (int)(v & 0xffffffffLL);
  int hi = (int)(v >> 32);
  lo = __shfl_xor(lo, m, 64);
  hi = __shfl_xor(hi, m, 64);
  return __longlong_as_double(((long long)hi << 32) | (u64)(u32)lo);
}

// One wave per row: rs[b*N+n] = sum_m c[b,n,m], f64 accum -> f32
__global__ __launch_bounds__(256) void k_rowsum(const float* __restrict__ c, float* __restrict__ rs) {
  int row = blockIdx.x * 4 + (threadIdx.x >> 6);   // 16384 rows total
  int lane = threadIdx.x & 63;
  const float4* r4 = (const float4*)(c + (size_t)row * MM);
  double acc = 0.0;
  #pragma unroll
  for (int k = 0; k < 8; ++k) {
    float4 v = r4[lane + k * 64];
    acc += (double)v.x + (double)v.y + (double)v.z + (double)v.w;
  }
  #pragma unroll
  for (int m = 32; m > 0; m >>= 1) acc += dshflxor(acc, m);
  if (lane == 0) rs[row] = (float)acc;
}

// Column partial sums over 64-row chunks (deterministic, no atomics)
__global__ __launch_bounds__(256) void k_colpart(const float* __restrict__ c, double* __restrict__ cp) {
  int col = blockIdx.x * 256 + threadIdx.x;  // 8 col tiles
  int rc  = blockIdx.y;                      // 32 row chunks
  int b   = blockIdx.z;                      // 8 batches
  const float* base = c + ((size_t)b * NN + (size_t)rc * 64) * MM + col;
  double acc = 0.0;
  #pragma unroll 8
  for (int r = 0; r < 64; ++r) acc += (double)base[(size_t)r * MM];
  cp[(size_t)(b * 32 + rc) * MM + col] = acc;
}

__global__ __launch_bounds__(256) void k_colsum(const double* __restrict__ cp, float* __restrict__ cs) {
  int idx = blockIdx.x * 256 + threadIdx.x;  // b*M+col, 16384 total
  int b = idx >> 11;
  int col = idx & (MM - 1);
  double acc = 0.0;
  #pragma unroll
  for (int rc = 0; rc < 32; ++rc) acc += cp[(size_t)(b * 32 + rc) * MM + col];
  cs[idx] = (float)acc;
}

// Per-batch histogram of score float-bits >> 18 (8192 bins, LDS then merge)
__global__ __launch_bounds__(256) void k_hist(const float* __restrict__ c, const float* __restrict__ rs,
                                              const float* __restrict__ cs, u32* __restrict__ ghist) {
  __shared__ u32 h[NBIN];
  for (int i = threadIdx.x; i < NBIN; i += 256) h[i] = 0;
  __syncthreads();
  int b = blockIdx.x >> 6;     // 64 blocks per batch
  int blk = blockIdx.x & 63;
  const float4* cb = (const float4*)(c + (size_t)b * NMTOT);
  const float* rsb = rs + b * NN;
  const float* csb = cs + b * MM;
  int base = blk * 16384;      // float4 index base within batch
  for (int it = 0; it < 64; ++it) {
    int v4 = base + it * 256 + threadIdx.x;
    float4 v = cb[v4];
    int fe = v4 << 2;
    int n = fe >> 11;
    int m = fe & (MM - 1);
    float rv = rsb[n];
    float s0 = (v.x / rv) * (v.x / csb[m]);
    float s1 = (v.y / rv) * (v.y / csb[m + 1]);
    float s2 = (v.z / rv) * (v.z / csb[m + 2]);
    float s3 = (v.w / rv) * (v.w / csb[m + 3]);
    atomicAdd(&h[__float_as_uint(s0) >> 18], 1u);
    atomicAdd(&h[__float_as_uint(s1) >> 18], 1u);
    atomicAdd(&h[__float_as_uint(s2) >> 18], 1u);
    atomicAdd(&h[__float_as_uint(s3) >> 18], 1u);
  }
  __syncthreads();
  u32* gh = ghist + b * NBIN;
  for (int i = threadIdx.x; i < NBIN; i += 256) {
    u32 x = h[i];
    if (x) atomicAdd(&gh[i], x);
  }
}

// Find per-batch threshold bin T: count(bin >= T) >= 256, count(bin > T) < 256
__global__ __launch_bounds__(256) void k_thresh(const u32* __restrict__ ghist, u32* __restrict__ T) {
  __shared__ u32 lsum[256];
  int b = blockIdx.x;
  const u32* gh = ghist + b * NBIN;
  int t = threadIdx.x;
  u32 s = 0;
  for (int k = 0; k < 32; ++k) s += gh[NBIN - 1 - (t * 32 + k)];
  lsum[t] = s;
  __syncthreads();
  if (t == 0) {
    u32 cum = 0; u32 thr = 0; bool found = false;
    for (int q = 0; q < 256 && !found; ++q) {
      if (cum + lsum[q] >= KK) {
        u32 c2 = cum;
        for (int k = 0; k < 32; ++k) {
          int bin = NBIN - 1 - (q * 32 + k);
          c2 += gh[bin];
          if (c2 >= KK) { thr = (u32)bin; found = true; break; }
        }
      } else {
        cum += lsum[q];
      }
    }
    T[b] = thr;
  }
}

// Recompute scores, append candidates with bin >= T[b]
__global__ __launch_bounds__(256) void k_collect(const float* __restrict__ c, const float* __restrict__ rs,
                                                 const float* __restrict__ cs, const u32* __restrict__ T,
                                                 u32* __restrict__ cnt, u64* __restrict__ cand) {
  int b = blockIdx.x >> 6;
  int blk = blockIdx.x & 63;
  const float4* cb = (const float4*)(c + (size_t)b * NMTOT);
  const float* rsb = rs + b * NN;
  const float* csb = cs + b * MM;
  u32 thr = T[b];
  u64* cd = cand + (size_t)b * CANDCAP;
  int base = blk * 16384;
  for (int it = 0; it < 64; ++it) {
    int v4 = base + it * 256 + threadIdx.x;
    float4 v = cb[v4];
    int fe = v4 << 2;
    int n = fe >> 11;
    int m = fe & (MM - 1);
    float rv = rsb[n];
    float s[4];
    s[0] = (v.x / rv) * (v.x / csb[m]);
    s[1] = (v.y / rv) * (v.y / csb[m + 1]);
    s[2] = (v.z / rv) * (v.z / csb[m + 2]);
    s[3] = (v.w / rv) * (v.w / csb[m + 3]);
    #pragma unroll
    for (int j = 0; j < 4; ++j) {
      u32 bits = __float_as_uint(s[j]);
      if ((bits >> 18) >= thr) {
        u32 pos = atomicAdd(&cnt[b], 1u);
        if (pos < CANDCAP) {
          u64 key = ((u64)bits << 32) | (u64)(0xFFFFFFFFu - (u32)(fe + j));
          cd[pos] = key;
        }
      }
    }
  }
}

// Per-batch bitonic sort (desc score, asc idx) of candidates, write top-256
__global__ __launch_bounds__(256) void k_sort(const u32* __restrict__ cnt, const u64* __restrict__ cand,
                                              float* __restrict__ out) {
  __shared__ u64 keys[CANDCAP];
  int b = blockIdx.x;
  u32 n = cnt[b]; if (n > CANDCAP) n = CANDCAP;
  const u64* cd = cand + (size_t)b * CANDCAP;
  for (int i = threadIdx.x; i < CANDCAP; i += 256)
    keys[i] = (i < (int)n) ? cd[i] : 0ull;
  for (int ssize = 2; ssize <= CANDCAP; ssize <<= 1) {
    for (int stride = ssize >> 1; stride > 0; stride >>= 1) {
      __syncthreads();
      for (int k = threadIdx.x; k < CANDCAP; k += 256) {
        int p = k ^ stride;
        if (p > k) {
          u64 a = keys[k], bb2 = keys[p];
          bool up = ((k & ssize) == 0);
          bool sw = up ? (a < bb2) : (a > bb2);
          if (sw) { keys[k] = bb2; keys[p] = a; }
        }
      }
    }
  }
  __syncthreads();
  int k = threadIdx.x;
  if (k < KK) {
    u64 key = keys[k];
    u32 idx = 0xFFFFFFFFu - (u32)(key & 0xFFFFFFFFull);
    float sc = __uint_as_float((u32)(key >> 32));
    out[b * KK + k]                 = (float)(idx >> 11);      // ref idx = n
    out[BB * KK + b * KK + k]       = (float)(idx & (MM - 1)); // src idx = m
    out[2 * BB * KK + b * KK + k]   = sc;                      // score
  }
}

extern "C" void kernel_launch(void* const* d_in, const int* in_sizes, int n_in,
                              void* d_out, int out_size, void* d_ws, size_t ws_size,
                              hipStream_t stream) {
  const float* c = (const float*)d_in[2];  // c_matrix [B,N,M]
  char* ws = (char*)d_ws;
  float*  rs    = (float*)(ws);                                   // 64 KiB
  float*  cs    = (float*)(ws + 65536);                           // 64 KiB
  double* cp    = (double*)(ws + 131072);                         // 4 MiB
  u32*    ghist = (u32*)(ws + 131072 + 4194304);                  // 256 KiB
  u32*    cnt   = (u32*)(ws + 131072 + 4194304 + NBIN * BB * 4);  // 256 B
  u32*    T     = (u32*)(ws + 131072 + 4194304 + NBIN * BB * 4 + 256);
  u64*    cand  = (u64*)(ws + 131072 + 4194304 + NBIN * BB * 4 + 512);
  float*  out   = (float*)d_out;

  hipMemsetAsync(ghist, 0, NBIN * BB * 4 + 256, stream);  // ghist + cnt

  k_rowsum <<<4096, 256, 0, stream>>>(c, rs);
  k_colpart<<<dim3(8, 32, 8), 256, 0, stream>>>(c, cp);
  k_colsum <<<64, 256, 0, stream>>>(cp, cs);
  k_hist   <<<512, 256, 0, stream>>>(c, rs, cs, ghist);
  k_thresh <<<8, 256, 0, stream>>>(ghist, T);
  k_collect<<<512, 256, 0, stream>>>(c, rs, cs, T, cnt, cand);
  k_sort   <<<8, 256, 0, stream>>>(cnt, cand, out);
}

// Round 4
// 381.113 us; speedup vs baseline: 1.2862x; 1.2862x over previous
//
#include <hip/hip_runtime.h>
#include <stdint.h>

#define BB 8
#define NN 2048
#define MM 2048
#define KK 256
#define NMTOT (NN*MM)
#define NBIN 8192
#define CANDCAP 4096

typedef unsigned int u32;
typedef unsigned long long u64;

__device__ inline double dshflxor(double x, int m) {
  long long v = __double_as_longlong(x);
  int lo = (int)(v & 0xffffffffLL);
  int hi = (int)(v >> 32);
  lo = __shfl_xor(lo, m, 64);
  hi = __shfl_xor(hi, m, 64);
  return __longlong_as_double(((long long)hi << 32) | (u64)(u32)lo);
}

// Fused: complete row sums for RCROWS rows + f64 column partials, one read of c.
// grid = (NN/RCROWS, BB), block = 256. Thread t owns float4 cols t and t+256.
template <int RCROWS>
__global__ __launch_bounds__(256) void k_sums(const float* __restrict__ c,
                                              float* __restrict__ rs,
                                              double* __restrict__ cp) {
  int rc = blockIdx.x;
  int b  = blockIdx.y;
  int t = threadIdx.x;
  int wave = t >> 6, lane = t & 63;
  const int NCH = NN / RCROWS;
  const float* base = c + ((size_t)b * NN + (size_t)rc * RCROWS) * MM;
  double ca[8] = {0, 0, 0, 0, 0, 0, 0, 0};
  __shared__ double rowpart[RCROWS][4];
  #pragma unroll 2
  for (int r = 0; r < RCROWS; ++r) {
    const float4* row4 = (const float4*)(base + (size_t)r * MM);
    float4 a = row4[t];
    float4 bq = row4[t + 256];
    ca[0] += (double)a.x;  ca[1] += (double)a.y;
    ca[2] += (double)a.z;  ca[3] += (double)a.w;
    ca[4] += (double)bq.x; ca[5] += (double)bq.y;
    ca[6] += (double)bq.z; ca[7] += (double)bq.w;
    double rp = (double)a.x + (double)a.y + (double)a.z + (double)a.w
              + (double)bq.x + (double)bq.y + (double)bq.z + (double)bq.w;
    #pragma unroll
    for (int m2 = 32; m2 > 0; m2 >>= 1) rp += dshflxor(rp, m2);
    if (lane == 0) rowpart[r][wave] = rp;
  }
  __syncthreads();
  if (t < RCROWS) {
    double s = rowpart[t][0] + rowpart[t][1] + rowpart[t][2] + rowpart[t][3];
    rs[b * NN + rc * RCROWS + t] = (float)s;
  }
  double* cpb = cp + ((size_t)(b * NCH + rc)) * MM;
  *(double4*)(cpb + 4 * t)        = make_double4(ca[0], ca[1], ca[2], ca[3]);
  *(double4*)(cpb + 1024 + 4 * t) = make_double4(ca[4], ca[5], ca[6], ca[7]);
}

__global__ __launch_bounds__(256) void k_colsum(const double* __restrict__ cp,
                                                float* __restrict__ cs, int nch) {
  int idx = blockIdx.x * 256 + threadIdx.x;  // b*M+col, 16384 total
  int b = idx >> 11;
  int col = idx & (MM - 1);
  double acc = 0.0;
  for (int q = 0; q < nch; ++q) acc += cp[(size_t)(b * nch + q) * MM + col];
  cs[idx] = (float)acc;
}

// Per-batch histogram of score float-bits >> 18 (8192 bins, LDS then merge)
__global__ __launch_bounds__(256) void k_hist(const float* __restrict__ c, const float* __restrict__ rs,
                                              const float* __restrict__ cs, u32* __restrict__ ghist) {
  __shared__ u32 h[NBIN];
  for (int i = threadIdx.x; i < NBIN; i += 256) h[i] = 0;
  __syncthreads();
  int b = blockIdx.x >> 6;     // 64 blocks per batch
  int blk = blockIdx.x & 63;
  const float4* cb = (const float4*)(c + (size_t)b * NMTOT);
  const float* rsb = rs + b * NN;
  const float* csb = cs + b * MM;
  int base = blk * 16384;      // float4 index base within batch
  for (int it = 0; it < 64; ++it) {
    int v4 = base + it * 256 + threadIdx.x;
    float4 v = cb[v4];
    int fe = v4 << 2;
    int n = fe >> 11;
    int m = fe & (MM - 1);
    float rv = rsb[n];
    float s0 = (v.x / rv) * (v.x / csb[m]);
    float s1 = (v.y / rv) * (v.y / csb[m + 1]);
    float s2 = (v.z / rv) * (v.z / csb[m + 2]);
    float s3 = (v.w / rv) * (v.w / csb[m + 3]);
    atomicAdd(&h[__float_as_uint(s0) >> 18], 1u);
    atomicAdd(&h[__float_as_uint(s1) >> 18], 1u);
    atomicAdd(&h[__float_as_uint(s2) >> 18], 1u);
    atomicAdd(&h[__float_as_uint(s3) >> 18], 1u);
  }
  __syncthreads();
  u32* gh = ghist + b * NBIN;
  for (int i = threadIdx.x; i < NBIN; i += 256) {
    u32 x = h[i];
    if (x) atomicAdd(&gh[i], x);
  }
}

// Find per-batch threshold bin T: count(bin >= T) >= 256, count(bin > T) < 256
__global__ __launch_bounds__(256) void k_thresh(const u32* __restrict__ ghist, u32* __restrict__ T) {
  __shared__ u32 lsum[256];
  int b = blockIdx.x;
  const u32* gh = ghist + b * NBIN;
  int t = threadIdx.x;
  u32 s = 0;
  for (int k = 0; k < 32; ++k) s += gh[NBIN - 1 - (t * 32 + k)];
  lsum[t] = s;
  __syncthreads();
  if (t == 0) {
    u32 cum = 0; u32 thr = 0; bool found = false;
    for (int q = 0; q < 256 && !found; ++q) {
      if (cum + lsum[q] >= KK) {
        u32 c2 = cum;
        for (int k = 0; k < 32; ++k) {
          int bin = NBIN - 1 - (q * 32 + k);
          c2 += gh[bin];
          if (c2 >= KK) { thr = (u32)bin; found = true; break; }
        }
      } else {
        cum += lsum[q];
      }
    }
    T[b] = thr;
  }
}

// Recompute scores, append candidates with bin >= T[b]
__global__ __launch_bounds__(256) void k_collect(const float* __restrict__ c, const float* __restrict__ rs,
                                                 const float* __restrict__ cs, const u32* __restrict__ T,
                                                 u32* __restrict__ cnt, u64* __restrict__ cand) {
  int b = blockIdx.x >> 6;
  int blk = blockIdx.x & 63;
  const float4* cb = (const float4*)(c + (size_t)b * NMTOT);
  const float* rsb = rs + b * NN;
  const float* csb = cs + b * MM;
  u32 thr = T[b];
  u64* cd = cand + (size_t)b * CANDCAP;
  int base = blk * 16384;
  for (int it = 0; it < 64; ++it) {
    int v4 = base + it * 256 + threadIdx.x;
    float4 v = cb[v4];
    int fe = v4 << 2;
    int n = fe >> 11;
    int m = fe & (MM - 1);
    float rv = rsb[n];
    float s[4];
    s[0] = (v.x / rv) * (v.x / csb[m]);
    s[1] = (v.y / rv) * (v.y / csb[m + 1]);
    s[2] = (v.z / rv) * (v.z / csb[m + 2]);
    s[3] = (v.w / rv) * (v.w / csb[m + 3]);
    #pragma unroll
    for (int j = 0; j < 4; ++j) {
      u32 bits = __float_as_uint(s[j]);
      if ((bits >> 18) >= thr) {
        u32 pos = atomicAdd(&cnt[b], 1u);
        if (pos < CANDCAP) {
          u64 key = ((u64)bits << 32) | (u64)(0xFFFFFFFFu - (u32)(fe + j));
          cd[pos] = key;
        }
      }
    }
  }
}

// Per-batch bitonic sort (desc score, asc idx), dynamic power-of-two size.
__global__ __launch_bounds__(256) void k_sort(const u32* __restrict__ cnt, const u64* __restrict__ cand,
                                              float* __restrict__ out) {
  __shared__ u64 keys[CANDCAP];
  int b = blockIdx.x;
  u32 n = cnt[b]; if (n > CANDCAP) n = CANDCAP;
  int size = 512;
  while (size < (int)n) size <<= 1;
  const u64* cd = cand + (size_t)b * CANDCAP;
  for (int i = threadIdx.x; i < size; i += 256)
    keys[i] = (i < (int)n) ? cd[i] : 0ull;
  for (int ssize = 2; ssize <= size; ssize <<= 1) {
    for (int stride = ssize >> 1; stride > 0; stride >>= 1) {
      __syncthreads();
      for (int k = threadIdx.x; k < size; k += 256) {
        int p = k ^ stride;
        if (p > k) {
          u64 a = keys[k], bb2 = keys[p];
          bool up = ((k & ssize) == 0);
          bool sw = up ? (a < bb2) : (a > bb2);
          if (sw) { keys[k] = bb2; keys[p] = a; }
        }
      }
    }
  }
  __syncthreads();
  int k = threadIdx.x;
  if (k < KK) {
    u64 key = keys[k];
    u32 idx = 0xFFFFFFFFu - (u32)(key & 0xFFFFFFFFull);
    float sc = __uint_as_float((u32)(key >> 32));
    out[b * KK + k]                 = (float)(idx >> 11);      // ref idx = n
    out[BB * KK + b * KK + k]       = (float)(idx & (MM - 1)); // src idx = m
    out[2 * BB * KK + b * KK + k]   = sc;                      // score
  }
}

extern "C" void kernel_launch(void* const* d_in, const int* in_sizes, int n_in,
                              void* d_out, int out_size, void* d_ws, size_t ws_size,
                              hipStream_t stream) {
  const float* c = (const float*)d_in[2];  // c_matrix [B,N,M]
  char* ws = (char*)d_ws;
  float* out = (float*)d_out;

  // Pick chunk granularity by available workspace: 32-row chunks need an
  // 8 MiB column-partial buffer; fall back to 64-row chunks (4 MiB, proven).
  const size_t cp32 = (size_t)BB * 64 * MM * 8;   // 8 MiB (64 chunks/batch)
  const size_t cp64 = (size_t)BB * 32 * MM * 8;   // 4 MiB (32 chunks/batch)
  bool use32 = ws_size >= (131072 + cp32 + NBIN * BB * 4 + 512 + (size_t)BB * CANDCAP * 8);
  size_t cpBytes = use32 ? cp32 : cp64;
  int nch = use32 ? 64 : 32;

  float*  rs    = (float*)(ws);                                   // 64 KiB
  float*  cs    = (float*)(ws + 65536);                           // 64 KiB
  double* cp    = (double*)(ws + 131072);
  u32*    ghist = (u32*)(ws + 131072 + cpBytes);
  u32*    cnt   = (u32*)(ws + 131072 + cpBytes + NBIN * BB * 4);
  u32*    T     = (u32*)(ws + 131072 + cpBytes + NBIN * BB * 4 + 256);
  u64*    cand  = (u64*)(ws + 131072 + cpBytes + NBIN * BB * 4 + 512);

  hipMemsetAsync(ghist, 0, NBIN * BB * 4 + 256, stream);  // ghist + cnt

  if (use32) k_sums<32><<<dim3(64, 8), 256, 0, stream>>>(c, rs, cp);
  else       k_sums<64><<<dim3(32, 8), 256, 0, stream>>>(c, rs, cp);
  k_colsum <<<64, 256, 0, stream>>>(cp, cs, nch);
  k_hist   <<<512, 256, 0, stream>>>(c, rs, cs, ghist);
  k_thresh <<<8, 256, 0, stream>>>(ghist, T);
  k_collect<<<512, 256, 0, stream>>>(c, rs, cs, T, cnt, cand);
  k_sort   <<<8, 256, 0, stream>>>(cnt, cand, out);
}

// Round 6
// 368.165 us; speedup vs baseline: 1.3314x; 1.0352x over previous
//
#include <hip/hip_runtime.h>
#include <stdint.h>

#define BB 8
#define NN 2048
#define MM 2048
#define KK 256
#define NMTOT (NN*MM)
#define NBIN 8192
#define CANDCAP 8192

typedef unsigned int u32;
typedef unsigned long long u64;

__device__ inline double dshflxor(double x, int m) {
  long long v = __double_as_longlong(x);
  int lo = (int)(v & 0xffffffffLL);
  int hi = (int)(v >> 32);
  lo = __shfl_xor(lo, m, 64);
  hi = __shfl_xor(hi, m, 64);
  return __longlong_as_double(((long long)hi << 32) | (u64)(u32)lo);
}

// Fused: complete row sums for RCROWS rows + f64 column partials, one read of c.
// grid = (NN/RCROWS, BB), block = 256. Thread t owns float4 cols t and t+256.
template <int RCROWS>
__global__ __launch_bounds__(256) void k_sums(const float* __restrict__ c,
                                              float* __restrict__ rs,
                                              double* __restrict__ cp) {
  int rc = blockIdx.x;
  int b  = blockIdx.y;
  int t = threadIdx.x;
  int wave = t >> 6, lane = t & 63;
  const int NCH = NN / RCROWS;
  const float* base = c + ((size_t)b * NN + (size_t)rc * RCROWS) * MM;
  double ca[8] = {0, 0, 0, 0, 0, 0, 0, 0};
  __shared__ double rowpart[RCROWS][4];
  #pragma unroll 2
  for (int r = 0; r < RCROWS; ++r) {
    const float4* row4 = (const float4*)(base + (size_t)r * MM);
    float4 a = row4[t];
    float4 bq = row4[t + 256];
    ca[0] += (double)a.x;  ca[1] += (double)a.y;
    ca[2] += (double)a.z;  ca[3] += (double)a.w;
    ca[4] += (double)bq.x; ca[5] += (double)bq.y;
    ca[6] += (double)bq.z; ca[7] += (double)bq.w;
    double rp = (double)a.x + (double)a.y + (double)a.z + (double)a.w
              + (double)bq.x + (double)bq.y + (double)bq.z + (double)bq.w;
    #pragma unroll
    for (int m2 = 32; m2 > 0; m2 >>= 1) rp += dshflxor(rp, m2);
    if (lane == 0) rowpart[r][wave] = rp;
  }
  __syncthreads();
  if (t < RCROWS) {
    double s = rowpart[t][0] + rowpart[t][1] + rowpart[t][2] + rowpart[t][3];
    rs[b * NN + rc * RCROWS + t] = (float)s;
  }
  double* cpb = cp + ((size_t)(b * NCH + rc)) * MM;
  *(double4*)(cpb + 4 * t)        = make_double4(ca[0], ca[1], ca[2], ca[3]);
  *(double4*)(cpb + 1024 + 4 * t) = make_double4(ca[4], ca[5], ca[6], ca[7]);
}

// Column totals + f32 reciprocals of both row and column sums (for the proxy
// score used in hist/collect; exact divides are reserved for final candidates).
__global__ __launch_bounds__(256) void k_colsum(const double* __restrict__ cp,
                                                const float* __restrict__ rs,
                                                float* __restrict__ cs,
                                                float* __restrict__ rrs,
                                                float* __restrict__ rcs, int nch) {
  int idx = blockIdx.x * 256 + threadIdx.x;  // b*M+col, 16384 total
  int b = idx >> 11;
  int col = idx & (MM - 1);
  double acc = 0.0;
  for (int q = 0; q < nch; ++q) acc += cp[(size_t)(b * nch + q) * MM + col];
  float csv = (float)acc;
  cs[idx] = csv;
  rcs[idx] = 1.0f / csv;
  rrs[idx] = 1.0f / rs[idx];   // same 16384 layout: b*N+row
}

// Per-batch histogram of PROXY score float-bits >> 18 (8192 bins).
// Proxy: s~ = (v*rrs[n])*(v*rcs[m]) — 3 muls, <=~4e-7 rel err vs exact.
__global__ __launch_bounds__(256) void k_hist(const float* __restrict__ c,
                                              const float* __restrict__ rrs,
                                              const float* __restrict__ rcs,
                                              u32* __restrict__ ghist) {
  __shared__ u32 h[NBIN];
  for (int i = threadIdx.x; i < NBIN; i += 256) h[i] = 0;
  __syncthreads();
  int b = blockIdx.x >> 7;     // 128 blocks per batch
  int blk = blockIdx.x & 127;
  const float4* cb = (const float4*)(c + (size_t)b * NMTOT);
  const float* rsb = rrs + b * NN;
  const float* csb = rcs + b * MM;
  int base = blk * 8192;       // float4 index base within batch
  for (int it = 0; it < 32; ++it) {
    int v4 = base + it * 256 + threadIdx.x;
    float4 v = cb[v4];
    int fe = v4 << 2;
    int n = fe >> 11;
    int m = fe & (MM - 1);
    float rv = rsb[n];
    float s0 = (v.x * rv) * (v.x * csb[m]);
    float s1 = (v.y * rv) * (v.y * csb[m + 1]);
    float s2 = (v.z * rv) * (v.z * csb[m + 2]);
    float s3 = (v.w * rv) * (v.w * csb[m + 3]);
    atomicAdd(&h[__float_as_uint(s0) >> 18], 1u);
    atomicAdd(&h[__float_as_uint(s1) >> 18], 1u);
    atomicAdd(&h[__float_as_uint(s2) >> 18], 1u);
    atomicAdd(&h[__float_as_uint(s3) >> 18], 1u);
  }
  __syncthreads();
  u32* gh = ghist + b * NBIN;
  for (int i = threadIdx.x; i < NBIN; i += 256) {
    u32 x = h[i];
    if (x) atomicAdd(&gh[i], x);
  }
}

// Find per-batch threshold bin T: count(bin >= T) >= 256, count(bin > T) < 256
__global__ __launch_bounds__(256) void k_thresh(const u32* __restrict__ ghist, u32* __restrict__ T) {
  __shared__ u32 lsum[256];
  int b = blockIdx.x;
  const u32* gh = ghist + b * NBIN;
  int t = threadIdx.x;
  u32 s = 0;
  for (int k = 0; k < 32; ++k) s += gh[NBIN - 1 - (t * 32 + k)];
  lsum[t] = s;
  __syncthreads();
  if (t == 0) {
    u32 cum = 0; u32 thr = 0; bool found = false;
    for (int q = 0; q < 256 && !found; ++q) {
      if (cum + lsum[q] >= KK) {
        u32 c2 = cum;
        for (int k = 0; k < 32; ++k) {
          int bin = NBIN - 1 - (q * 32 + k);
          c2 += gh[bin];
          if (c2 >= KK) { thr = (u32)bin; found = true; break; }
        }
      } else {
        cum += lsum[q];
      }
    }
    T[b] = thr;
  }
}

// Append candidate indices whose proxy bits pass bin T with a 16-ulp slack
// (1.9e-6 relative — covers the <=4e-7 proxy-vs-exact error; the true
// top-256 is provably a subset; expected sliver additions O(1)).
__global__ __launch_bounds__(256) void k_collect(const float* __restrict__ c,
                                                 const float* __restrict__ rrs,
                                                 const float* __restrict__ rcs,
                                                 const u32* __restrict__ T,
                                                 u32* __restrict__ cnt, u32* __restrict__ cand) {
  int b = blockIdx.x >> 7;
  int blk = blockIdx.x & 127;
  const float4* cb = (const float4*)(c + (size_t)b * NMTOT);
  const float* rsb = rrs + b * NN;
  const float* csb = rcs + b * MM;
  u32 thr = T[b];
  u32* cd = cand + (size_t)b * CANDCAP;
  int base = blk * 8192;
  for (int it = 0; it < 32; ++it) {
    int v4 = base + it * 256 + threadIdx.x;
    float4 v = cb[v4];
    int fe = v4 << 2;
    int n = fe >> 11;
    int m = fe & (MM - 1);
    float rv = rsb[n];
    float s[4];
    s[0] = (v.x * rv) * (v.x * csb[m]);
    s[1] = (v.y * rv) * (v.y * csb[m + 1]);
    s[2] = (v.z * rv) * (v.z * csb[m + 2]);
    s[3] = (v.w * rv) * (v.w * csb[m + 3]);
    #pragma unroll
    for (int j = 0; j < 4; ++j) {
      u32 bits = __float_as_uint(s[j]);
      if (((bits + 16u) >> 18) >= thr) {
        u32 pos = atomicAdd(&cnt[b], 1u);
        if (pos < CANDCAP) cd[pos] = (u32)(fe + j);
      }
    }
  }
}

// Per-batch: gather candidates, recompute EXACT score (IEEE divides, matching
// the reference formula), bitonic sort (desc score, asc idx), write top-256.
__global__ __launch_bounds__(256) void k_sort(const u32* __restrict__ cnt, const u32* __restrict__ cand,
                                              const float* __restrict__ c,
                                              const float* __restrict__ rs,
                                              const float* __restrict__ cs,
                                              float* __restrict__ out) {
  __shared__ u64 keys[CANDCAP];
  int b = blockIdx.x;
  u32 n = cnt[b]; if (n > CANDCAP) n = CANDCAP;
  int size = 512;
  while (size < (int)n) size <<= 1;
  const u32* cd = cand + (size_t)b * CANDCAP;
  const float* cb = c + (size_t)b * NMTOT;
  const float* rsb = rs + b * NN;
  const float* csb = cs + b * MM;
  for (int i = threadIdx.x; i < size; i += 256) {
    u64 key = 0ull;
    if (i < (int)n) {
      u32 idx = cd[i];
      float v = cb[idx];
      float sc = (v / rsb[idx >> 11]) * (v / csb[idx & (MM - 1)]);
      key = ((u64)__float_as_uint(sc) << 32) | (u64)(0xFFFFFFFFu - idx);
    }
    keys[i] = key;
  }
  for (int ssize = 2; ssize <= size; ssize <<= 1) {
    for (int stride = ssize >> 1; stride > 0; stride >>= 1) {
      __syncthreads();
      for (int k = threadIdx.x; k < size; k += 256) {
        int p = k ^ stride;
        if (p > k) {
          u64 a = keys[k], bb2 = keys[p];
          bool up = ((k & ssize) == 0);
          bool sw = up ? (a < bb2) : (a > bb2);
          if (sw) { keys[k] = bb2; keys[p] = a; }
        }
      }
    }
  }
  __syncthreads();
  int k = threadIdx.x;
  if (k < KK) {
    u64 key = keys[k];
    u32 idx = 0xFFFFFFFFu - (u32)(key & 0xFFFFFFFFull);
    float sc = __uint_as_float((u32)(key >> 32));
    out[b * KK + k]                 = (float)(idx >> 11);      // ref idx = n
    out[BB * KK + b * KK + k]       = (float)(idx & (MM - 1)); // src idx = m
    out[2 * BB * KK + b * KK + k]   = sc;                      // score
  }
}

extern "C" void kernel_launch(void* const* d_in, const int* in_sizes, int n_in,
                              void* d_out, int out_size, void* d_ws, size_t ws_size,
                              hipStream_t stream) {
  const float* c = (const float*)d_in[2];  // c_matrix [B,N,M]
  char* ws = (char*)d_ws;
  float* out = (float*)d_out;

  const size_t cp32 = (size_t)BB * 64 * MM * 8;   // 8 MiB (64 chunks/batch)
  const size_t cp64 = (size_t)BB * 32 * MM * 8;   // 4 MiB (32 chunks/batch)
  const size_t fixedHead = 4 * 65536;             // rs, cs, rrs, rcs
  const size_t tail = (size_t)NBIN * BB * 4 + 512 + (size_t)BB * CANDCAP * 4;
  bool use32 = ws_size >= (fixedHead + cp32 + tail);
  size_t cpBytes = use32 ? cp32 : cp64;
  int nch = use32 ? 64 : 32;

  float*  rs    = (float*)(ws);
  float*  cs    = (float*)(ws + 65536);
  float*  rrs   = (float*)(ws + 131072);
  float*  rcs   = (float*)(ws + 196608);
  double* cp    = (double*)(ws + fixedHead);
  u32*    ghist = (u32*)(ws + fixedHead + cpBytes);
  u32*    cnt   = (u32*)(ws + fixedHead + cpBytes + (size_t)NBIN * BB * 4);
  u32*    T     = (u32*)(ws + fixedHead + cpBytes + (size_t)NBIN * BB * 4 + 64);
  u32*    cand  = (u32*)(ws + fixedHead + cpBytes + (size_t)NBIN * BB * 4 + 512);

  hipMemsetAsync(ghist, 0, (size_t)NBIN * BB * 4 + 512, stream);  // ghist + cnt + T

  if (use32) k_sums<32><<<dim3(64, 8), 256, 0, stream>>>(c, rs, cp);
  else       k_sums<64><<<dim3(32, 8), 256, 0, stream>>>(c, rs, cp);
  k_colsum <<<64, 256, 0, stream>>>(cp, rs, cs, rrs, rcs, nch);
  k_hist   <<<1024, 256, 0, stream>>>(c, rrs, rcs, ghist);
  k_thresh <<<8, 256, 0, stream>>>(ghist, T);
  k_collect<<<1024, 256, 0, stream>>>(c, rrs, rcs, T, cnt, cand);
  k_sort   <<<8, 256, 0, stream>>>(cnt, cand, c, rs, cs, out);
}